// Round 1
// baseline (148.095 us; speedup 1.0000x reference)
//
#include <hip/hip_runtime.h>

// FocalBCELoss: loss = -mean( t*log(p)*(1-p)^2*alpha[c] + (1-t)*log(1-p)*p^2 )
// N=262144, C=64, GAMMA=2. Memory-bound streaming reduction over 128 MiB.

constexpr int N_ELEM = 262144 * 64;       // 16,777,216
constexpr int N_VEC4 = N_ELEM / 4;        // 4,194,304 float4s
constexpr int BLOCK  = 256;
constexpr int GRID1  = 2048;              // stage-1 blocks -> 2048 partials

__device__ __forceinline__ float focal_term(float p, float t, float a) {
    float lp   = logf(p);
    float l1p  = logf(1.0f - p);
    float omp  = 1.0f - p;
    float left  = t * lp * (omp * omp) * a;
    float right = (1.0f - t) * l1p * (p * p);
    return left + right;
}

__global__ __launch_bounds__(BLOCK) void focal_partial_kernel(
        const float4* __restrict__ p4,
        const float4* __restrict__ t4,
        const float*  __restrict__ alpha,
        float* __restrict__ partials) {
    __shared__ float s_alpha[64];
    if (threadIdx.x < 64) s_alpha[threadIdx.x] = alpha[threadIdx.x];
    __syncthreads();

    float acc = 0.0f;
    const int stride = GRID1 * BLOCK;
    for (int i = blockIdx.x * BLOCK + threadIdx.x; i < N_VEC4; i += stride) {
        float4 p = p4[i];
        float4 t = t4[i];
        int c0 = (i * 4) & 63;   // C=64, vec4-aligned: 4 consecutive channels
        acc += focal_term(p.x, t.x, s_alpha[c0 + 0]);
        acc += focal_term(p.y, t.y, s_alpha[c0 + 1]);
        acc += focal_term(p.z, t.z, s_alpha[c0 + 2]);
        acc += focal_term(p.w, t.w, s_alpha[c0 + 3]);
    }

    // wave64 shuffle reduce
    for (int off = 32; off > 0; off >>= 1)
        acc += __shfl_down(acc, off, 64);

    __shared__ float s_wave[BLOCK / 64];
    const int lane = threadIdx.x & 63;
    const int wid  = threadIdx.x >> 6;
    if (lane == 0) s_wave[wid] = acc;
    __syncthreads();
    if (threadIdx.x == 0)
        partials[blockIdx.x] = s_wave[0] + s_wave[1] + s_wave[2] + s_wave[3];
}

__global__ __launch_bounds__(BLOCK) void focal_final_kernel(
        const float* __restrict__ partials,
        float* __restrict__ out) {
    double acc = 0.0;
    for (int i = threadIdx.x; i < GRID1; i += BLOCK)
        acc += (double)partials[i];

    for (int off = 32; off > 0; off >>= 1)
        acc += __shfl_down(acc, off, 64);

    __shared__ double s_wave[BLOCK / 64];
    const int lane = threadIdx.x & 63;
    const int wid  = threadIdx.x >> 6;
    if (lane == 0) s_wave[wid] = acc;
    __syncthreads();
    if (threadIdx.x == 0) {
        double total = s_wave[0] + s_wave[1] + s_wave[2] + s_wave[3];
        out[0] = (float)(-total / (double)N_ELEM);
    }
}

extern "C" void kernel_launch(void* const* d_in, const int* in_sizes, int n_in,
                              void* d_out, int out_size, void* d_ws, size_t ws_size,
                              hipStream_t stream) {
    const float4* p4    = (const float4*)d_in[0];   // inputs  [N,C] fp32
    const float4* t4    = (const float4*)d_in[1];   // targets [N,C] fp32
    const float*  alpha = (const float*)d_in[2];    // alpha   [C]   fp32
    float* out      = (float*)d_out;
    float* partials = (float*)d_ws;                 // 2048 floats, written fully each call

    focal_partial_kernel<<<GRID1, BLOCK, 0, stream>>>(p4, t4, alpha, partials);
    focal_final_kernel<<<1, BLOCK, 0, stream>>>(partials, out);
}

// Round 2
// 146.403 us; speedup vs baseline: 1.0116x; 1.0116x over previous
//
#include <hip/hip_runtime.h>

// FocalBCELoss: loss = -mean( t*log(p)*(1-p)^2*alpha[c] + (1-t)*log(1-p)*p^2 )
// N=262144, C=64, GAMMA=2.
// t is exactly 0/1  =>  term = log(q)*w,  q = t?p:(1-p),  w = t?(1-p)^2*a : p^2
// One v_log_f32 per element, FMA-blended select, 8 loads in flight per thread.

constexpr int N_ELEM = 262144 * 64;       // 16,777,216
constexpr int N_VEC4 = N_ELEM / 4;        // 4,194,304 float4s
constexpr int BLOCK  = 256;
constexpr int ITERS  = 4;                 // float4s per thread
constexpr int TILE   = BLOCK * ITERS;     // 1024 float4s per block
constexpr int GRID1  = N_VEC4 / TILE;     // 4096 blocks

__device__ __forceinline__ float focal_term(float p, float t, float a) {
    float u  = 1.0f - p;
    float d  = p - u;                       // 2p-1
    float q  = fmaf(t, d, u);               // t? p : 1-p   (exact: t in {0,1})
    float lg = __logf(q);                   // single fast log
    float wa = u * u * a;                   // t=1 weight
    float pp = p * p;                       // t=0 weight
    float w  = fmaf(t, wa - pp, pp);        // t? wa : pp
    return lg * w;
}

__global__ __launch_bounds__(BLOCK) void focal_partial_kernel(
        const float4* __restrict__ p4,
        const float4* __restrict__ t4,
        const float*  __restrict__ alpha,
        float* __restrict__ partials) {
    const int tid  = threadIdx.x;
    const int base = blockIdx.x * TILE + tid;

    // Block tile base is a multiple of 1024 elements (== 0 mod C), and the
    // k-stride is 256 float4 = 1024 elements (== 0 mod C): each thread's 4
    // channels are fixed for the whole kernel. Hoist alpha into registers.
    const int c0 = (tid * 4) & 63;
    const float a0 = alpha[c0 + 0];
    const float a1 = alpha[c0 + 1];
    const float a2 = alpha[c0 + 2];
    const float a3 = alpha[c0 + 3];

    float4 P[ITERS], T[ITERS];
#pragma unroll
    for (int k = 0; k < ITERS; ++k) P[k] = p4[base + k * BLOCK];
#pragma unroll
    for (int k = 0; k < ITERS; ++k) T[k] = t4[base + k * BLOCK];

    float acc = 0.0f;
#pragma unroll
    for (int k = 0; k < ITERS; ++k) {
        acc += focal_term(P[k].x, T[k].x, a0);
        acc += focal_term(P[k].y, T[k].y, a1);
        acc += focal_term(P[k].z, T[k].z, a2);
        acc += focal_term(P[k].w, T[k].w, a3);
    }

    // wave64 shuffle reduce
    for (int off = 32; off > 0; off >>= 1)
        acc += __shfl_down(acc, off, 64);

    __shared__ float s_wave[BLOCK / 64];
    const int lane = tid & 63;
    const int wid  = tid >> 6;
    if (lane == 0) s_wave[wid] = acc;
    __syncthreads();
    if (tid == 0)
        partials[blockIdx.x] = s_wave[0] + s_wave[1] + s_wave[2] + s_wave[3];
}

__global__ __launch_bounds__(BLOCK) void focal_final_kernel(
        const float* __restrict__ partials,
        float* __restrict__ out) {
    double acc = 0.0;
    for (int i = threadIdx.x; i < GRID1; i += BLOCK)
        acc += (double)partials[i];

    for (int off = 32; off > 0; off >>= 1)
        acc += __shfl_down(acc, off, 64);

    __shared__ double s_wave[BLOCK / 64];
    const int lane = threadIdx.x & 63;
    const int wid  = threadIdx.x >> 6;
    if (lane == 0) s_wave[wid] = acc;
    __syncthreads();
    if (threadIdx.x == 0) {
        double total = s_wave[0] + s_wave[1] + s_wave[2] + s_wave[3];
        out[0] = (float)(-total / (double)N_ELEM);
    }
}

extern "C" void kernel_launch(void* const* d_in, const int* in_sizes, int n_in,
                              void* d_out, int out_size, void* d_ws, size_t ws_size,
                              hipStream_t stream) {
    const float4* p4    = (const float4*)d_in[0];   // inputs  [N,C] fp32
    const float4* t4    = (const float4*)d_in[1];   // targets [N,C] fp32
    const float*  alpha = (const float*)d_in[2];    // alpha   [C]   fp32
    float* out      = (float*)d_out;
    float* partials = (float*)d_ws;                 // GRID1 floats, fully rewritten each call

    focal_partial_kernel<<<GRID1, BLOCK, 0, stream>>>(p4, t4, alpha, partials);
    focal_final_kernel<<<1, BLOCK, 0, stream>>>(partials, out);
}